// Round 8
// baseline (826.720 us; speedup 1.0000x reference)
//
#include <hip/hip_runtime.h>
#include <hip/hip_bf16.h>
#include <hip/hip_cooperative_groups.h>
#include <math.h>

namespace cg = cooperative_groups;

#define N_NODES 50000
#define N_EDGES 800000
#define IN_DIM  128
#define HC_DIM  128
#define HID_C   32
#define SCAN_NB 196   // ceil(50000/256)
#define COOP_NB 512   // cooperative grid (2 blocks/CU -- safely co-resident)

typedef __attribute__((ext_vector_type(8))) short short8;   // 8 bf16 = 4 VGPR (MFMA A/B frag)
typedef __attribute__((ext_vector_type(4))) short short4v;
typedef __attribute__((ext_vector_type(4))) float f32x4;    // MFMA C/D frag

__device__ __forceinline__ float gelu_f(float x){
    return 0.5f*x*(1.0f + erff(x*0.7071067811865475f));
}

// fp32 -> (hi, lo) bf16 split: hi = rn(f), lo = rn(f - hi). hi*hi+hi*lo+lo*hi ~ fp32.
__device__ __forceinline__ void split2(float f, short& h, short& l){
    __hip_bfloat16 bh = __float2bfloat16(f);
    float r = f - __bfloat162float(bh);
    __hip_bfloat16 blo = __float2bfloat16(r);
    h = *reinterpret_cast<short*>(&bh);
    l = *reinterpret_cast<short*>(&blo);
}
__device__ __forceinline__ unsigned short f2bf(float f){
    __hip_bfloat16 b = __float2bfloat16(f);
    return *reinterpret_cast<unsigned short*>(&b);
}
__device__ __forceinline__ float bf2f(unsigned short u){
    return __uint_as_float(((unsigned)u)<<16);
}

// ---------------- cooperative setup: splitW + zero + input-proj + CSR ----------------
struct SetupArgs {
    const float* x; const float* Win; const float* bin;
    float* h; short* hhi; short* hlo;
    const int* src; const int* dst;
    int* cursor; int* rowptr; int* part; int* colidx;
    const float* W[7];
    short* WT;
};

__global__ __launch_bounds__(256) void k_setup(SetupArgs a){
    cg::grid_group grid = cg::this_grid();
    __shared__ int sh[256];
    int t = threadIdx.x;
    int gtid = blockIdx.x*256 + t;
    const int gsize = COOP_NB*256;

    // --- phase A: zero cursor ---
    for(int i=gtid; i<N_NODES; i+=gsize) a.cursor[i]=0;
    // --- phase A: split 7 weight matrices into transposed hi/lo bf16 [n][k] ---
    // WT offsets (shorts): m0@0(K32) m1@8192(K32) m2@16384 m3@49152 m4@81920 m5@114688 m6@147456
    for(int widx=gtid; widx<90112; widx+=gsize){
        int m, e;
        if(widx<4096){ m=0; e=widx; }
        else if(widx<8192){ m=1; e=widx-4096; }
        else { m = 2+(widx-8192)/16384; e = (widx-8192)%16384; }
        int K = (m<2)?32:128;
        size_t off;
        switch(m){
            case 0: off=0; break;      case 1: off=8192; break;
            case 2: off=16384; break;  case 3: off=49152; break;
            case 4: off=81920; break;  case 5: off=114688; break;
            default: off=147456; break;
        }
        int n = e & 127, k = e >> 7;
        float f = a.W[m][(size_t)k*HC_DIM + n];
        short h,l; split2(f,h,l);
        a.WT[off + (size_t)n*K + k] = h;
        a.WT[off + (size_t)K*HC_DIM + (size_t)n*K + k] = l;
    }
    // --- phase A: input projection h = gelu(x@Win+bin), emit fp32 + hi/lo bf16 ---
    for(int oid=gtid; oid<N_NODES*HID_C; oid+=gsize){
        int r = oid>>5, c = oid&31;
        const float4* x4 = (const float4*)(a.x + (size_t)r*IN_DIM);
        float acc=0.f;
        #pragma unroll 8
        for(int k=0;k<IN_DIM/4;k++){
            float4 xv = x4[k];
            acc = fmaf(xv.x, a.Win[(4*k  )*HID_C+c], acc);
            acc = fmaf(xv.y, a.Win[(4*k+1)*HID_C+c], acc);
            acc = fmaf(xv.z, a.Win[(4*k+2)*HID_C+c], acc);
            acc = fmaf(xv.w, a.Win[(4*k+3)*HID_C+c], acc);
        }
        float v = gelu_f(acc + a.bin[c]);
        a.h[oid] = v;
        short hh,ll; split2(v,hh,ll);
        a.hhi[oid]=hh; a.hlo[oid]=ll;
    }
    grid.sync();
    // --- phase B: degree count ---
    for(int e=gtid; e<N_EDGES; e+=gsize) atomicAdd(&a.cursor[a.dst[e]], 1);
    grid.sync();
    // --- phase C: per-chunk scan ---
    if(blockIdx.x < SCAN_NB){
        int i = blockIdx.x*256 + t;
        int v = (i<N_NODES)? a.cursor[i] : 0;
        sh[t]=v; __syncthreads();
        for(int off=1; off<256; off<<=1){
            int y = (t>=off)? sh[t-off] : 0;
            __syncthreads();
            sh[t] += y;
            __syncthreads();
        }
        if(i<N_NODES) a.rowptr[i] = sh[t]-v;
        if(t==255) a.part[blockIdx.x] = sh[255];
    }
    grid.sync();
    // --- phase D: scan chunk totals (block 0) ---
    if(blockIdx.x==0){
        int v = (t<SCAN_NB)? a.part[t] : 0;
        sh[t]=v; __syncthreads();
        for(int off=1; off<256; off<<=1){
            int y = (t>=off)? sh[t-off] : 0;
            __syncthreads();
            sh[t] += y;
            __syncthreads();
        }
        if(t<SCAN_NB) a.part[t] = sh[t]-v;
    }
    grid.sync();
    // --- phase E: add block offsets ---
    if(blockIdx.x < SCAN_NB){
        int i = blockIdx.x*256 + t;
        if(i<N_NODES){
            int v = a.rowptr[i] + a.part[blockIdx.x];
            a.rowptr[i]=v; a.cursor[i]=v;
        }
        if(i==0) a.rowptr[N_NODES]=N_EDGES;
    }
    grid.sync();
    // --- phase F: fill CSR ---
    for(int e=gtid; e<N_EDGES; e+=gsize){
        int d = a.dst[e];
        int p = atomicAdd(&a.cursor[d], 1);
        a.colidx[p] = a.src[e];
    }
}

// ---------------- full-width MFMA GEMM (bf16x3, ~fp32) ----------------
// C[64 rows x 128 cols] = A@W (+pair). Block 256 thr = 4 waves; wave w owns
// n-subtiles {w*16, 64+w*16}; 4 m-tiles of 16 rows; per K-chunk(32):
// 16 ds_read_b128 : 48 MFMA (PAIR). A-frag A[m=lane&15][k=quad*8+j];
// B-frag from WT[n][k]; C/D col=lane&15, row=quad*4+reg (verified r6/r7).
// NORM variant (single matrix) fuses bias + row-L2-normalize, writes final out.
template<int K, bool PAIR, bool NORM>
__global__ __launch_bounds__(256) void k_mfma(const short* __restrict__ Ahi, const short* __restrict__ Alo,
                                              const short* __restrict__ WTl, const float* __restrict__ bl,
                                              const short* __restrict__ WTr, const float* __restrict__ br,
                                              float* __restrict__ XL, unsigned short* __restrict__ XR16){
    constexpr int LDS_K = 40;          // 32 + 8 pad shorts (80B rows)
    constexpr int NCH = K / 32;
    __shared__ short As_hi[64*LDS_K], As_lo[64*LDS_K];
    __shared__ short Bh0[128*LDS_K], Bl0[128*LDS_K];
    __shared__ short Bh1[PAIR?128*LDS_K:1], Bl1[PAIR?128*LDS_K:1];
    __shared__ float ssq[NORM?256:1];

    int t = threadIdx.x;
    int lane = t & 63, wave = t >> 6;
    int quad = lane >> 4, ml = lane & 15;
    int rbase = blockIdx.x * 64;

    const short* WTl_lo = WTl + (size_t)K*HC_DIM;
    const short* WTr_lo = PAIR ? (WTr + (size_t)K*HC_DIM) : nullptr;

    f32x4 accL[4][2], accR[4][2];
    #pragma unroll
    for(int i=0;i<4;i++)
        #pragma unroll
        for(int j=0;j<2;j++){ accL[i][j]=(f32x4){0,0,0,0}; accR[i][j]=(f32x4){0,0,0,0}; }

    int r = t >> 2, seg = t & 3;
    int gr = rbase + r; if(gr >= N_NODES) gr = N_NODES-1;

    for(int c=0; c<NCH; c++){
        if(c) __syncthreads();
        size_t ka = (size_t)gr*K + c*32 + seg*8;
        *(short8*)(As_hi + r*LDS_K + seg*8) = *(const short8*)(Ahi + ka);
        *(short8*)(As_lo + r*LDS_K + seg*8) = *(const short8*)(Alo + ka);
        #pragma unroll
        for(int u=0; u<2; u++){
            int uu = t + u*256;
            int n = uu >> 2, sg = uu & 3;
            size_t kw = (size_t)n*K + c*32 + sg*8;
            *(short8*)(Bh0 + n*LDS_K + sg*8) = *(const short8*)(WTl + kw);
            *(short8*)(Bl0 + n*LDS_K + sg*8) = *(const short8*)(WTl_lo + kw);
            if(PAIR){
                *(short8*)(Bh1 + n*LDS_K + sg*8) = *(const short8*)(WTr + kw);
                *(short8*)(Bl1 + n*LDS_K + sg*8) = *(const short8*)(WTr_lo + kw);
            }
        }
        __syncthreads();

        int k0 = quad*8;
        short8 ah[4], al[4];
        #pragma unroll
        for(int i=0;i<4;i++){
            ah[i] = *(const short8*)(As_hi + (16*i + ml)*LDS_K + k0);
            al[i] = *(const short8*)(As_lo + (16*i + ml)*LDS_K + k0);
        }
        #pragma unroll
        for(int j=0;j<2;j++){
            int nrow = j*64 + wave*16 + ml;
            short8 bh = *(const short8*)(Bh0 + nrow*LDS_K + k0);
            short8 blo = *(const short8*)(Bl0 + nrow*LDS_K + k0);
            #pragma unroll
            for(int i=0;i<4;i++){
                accL[i][j] = __builtin_amdgcn_mfma_f32_16x16x32_bf16(ah[i], bh,  accL[i][j], 0,0,0);
                accL[i][j] = __builtin_amdgcn_mfma_f32_16x16x32_bf16(ah[i], blo, accL[i][j], 0,0,0);
                accL[i][j] = __builtin_amdgcn_mfma_f32_16x16x32_bf16(al[i], bh,  accL[i][j], 0,0,0);
            }
            if(PAIR){
                short8 ch = *(const short8*)(Bh1 + nrow*LDS_K + k0);
                short8 cl = *(const short8*)(Bl1 + nrow*LDS_K + k0);
                #pragma unroll
                for(int i=0;i<4;i++){
                    accR[i][j] = __builtin_amdgcn_mfma_f32_16x16x32_bf16(ah[i], ch, accR[i][j], 0,0,0);
                    accR[i][j] = __builtin_amdgcn_mfma_f32_16x16x32_bf16(ah[i], cl, accR[i][j], 0,0,0);
                    accR[i][j] = __builtin_amdgcn_mfma_f32_16x16x32_bf16(al[i], ch, accR[i][j], 0,0,0);
                }
            }
        }
    }

    int col0 = wave*16 + ml, col1 = 64 + wave*16 + ml;
    float bL0 = bl[col0], bL1 = bl[col1];

    if(NORM){
        // fused bias + row-L2-normalize; write final out (XL = out)
        #pragma unroll
        for(int i=0;i<4;i++){
            #pragma unroll
            for(int rr=0;rr<4;rr++){
                float v0 = accL[i][0][rr] + bL0;
                float v1 = accL[i][1][rr] + bL1;
                float p = v0*v0 + v1*v1;
                p += __shfl_xor(p,1); p += __shfl_xor(p,2);
                p += __shfl_xor(p,4); p += __shfl_xor(p,8);
                if(ml==0) ssq[wave*64 + 16*i + quad*4 + rr] = p;
            }
        }
        __syncthreads();
        #pragma unroll
        for(int i=0;i<4;i++){
            #pragma unroll
            for(int rr=0;rr<4;rr++){
                int row = 16*i + quad*4 + rr;
                int grr = rbase + row;
                if(grr < N_NODES){
                    float tot = ssq[row] + ssq[64+row] + ssq[128+row] + ssq[192+row];
                    float inv = 1.0f / fmaxf(sqrtf(tot), 1e-12f);
                    XL[(size_t)grr*HC_DIM + col0] = (accL[i][0][rr] + bL0) * inv;
                    XL[(size_t)grr*HC_DIM + col1] = (accL[i][1][rr] + bL1) * inv;
                }
            }
        }
    } else {
        float bR0 = PAIR ? br[col0] : 0.f, bR1 = PAIR ? br[col1] : 0.f;
        #pragma unroll
        for(int i=0;i<4;i++){
            #pragma unroll
            for(int rr=0;rr<4;rr++){
                int grr = rbase + 16*i + quad*4 + rr;
                if(grr < N_NODES){
                    XL[(size_t)grr*HC_DIM + col0] = accL[i][0][rr] + bL0;
                    XL[(size_t)grr*HC_DIM + col1] = accL[i][1][rr] + bL1;
                    if(PAIR){
                        XR16[(size_t)grr*HC_DIM + col0] = f2bf(accR[i][0][rr] + bR0);
                        XR16[(size_t)grr*HC_DIM + col1] = f2bf(accR[i][1][rr] + bR1);
                    }
                }
            }
        }
    }
}

// ---------------- fused per-node GATv2 (XR in bf16) ----------------
// one wave per node; cg = lane&31 owns channels [4cg..4cg+4), half = lane>>5 owns
// alternate edges; 3-shfl head-dot over 8 lanes serves 2 edges/inst. Epilogue:
// bias + LayerNorm + GELU + residual, emits fp32 h + bf16 hi/lo for next GEMM.
__global__ __launch_bounds__(256) void k_node(const float* __restrict__ XL, const unsigned short* __restrict__ XR,
    const int* __restrict__ rowptr, const int* __restrict__ colidx,
    const float* __restrict__ att, const float* __restrict__ bo,
    const float* __restrict__ gg, const float* __restrict__ be,
    const float* __restrict__ hold, float* __restrict__ hout,
    short* __restrict__ hi_out, short* __restrict__ lo_out)
{
    int wave=threadIdx.x>>6, lane=threadIdx.x&63;
    int node = blockIdx.x*4+wave;
    int cg = lane & 31, half = lane >> 5;
    int c4 = cg << 2;

    float4 xl = *(const float4*)(XL + (size_t)node*HC_DIM + c4);
    float4 av = *(const float4*)(att + c4);
    int beg = rowptr[node], end = rowptr[node+1];

    #define LOADX(j, xx) { ushort4 u_ = *(const ushort4*)(XR + (size_t)(j)*HC_DIM + c4); \
        xx = make_float4(bf2f(u_.x), bf2f(u_.y), bf2f(u_.z), bf2f(u_.w)); }
    #define EDGE_LOGIT(xj, q) { \
        float u0 = xl.x + xj.x; u0 = (u0>0.f)?u0:0.2f*u0; \
        float u1 = xl.y + xj.y; u1 = (u1>0.f)?u1:0.2f*u1; \
        float u2 = xl.z + xj.z; u2 = (u2>0.f)?u2:0.2f*u2; \
        float u3 = xl.w + xj.w; u3 = (u3>0.f)?u3:0.2f*u3; \
        q = fmaf(u0,av.x, fmaf(u1,av.y, fmaf(u2,av.z, u3*av.w))); \
        q += __shfl_xor(q,1); q += __shfl_xor(q,2); q += __shfl_xor(q,4); }

    float4 xs; LOADX(node, xs)
    float qs; EDGE_LOGIT(xs, qs)
    float m, ls; float4 acc;
    if(half==0){ m = qs; ls = 1.f; acc = xs; }
    else       { m = -INFINITY; ls = 0.f; acc = make_float4(0.f,0.f,0.f,0.f); }

    int P = end - beg;
    int nb = P >> 3;
    int base = beg;
    for(int b=0; b<nb; b++, base += 8){
        int j0 = colidx[base     + half];
        int j1 = colidx[base + 2 + half];
        int j2 = colidx[base + 4 + half];
        int j3 = colidx[base + 6 + half];
        float4 x0, x1, x2, x3;
        LOADX(j0, x0) LOADX(j1, x1) LOADX(j2, x2) LOADX(j3, x3)
        float q0,q1,q2,q3;
        EDGE_LOGIT(x0,q0) EDGE_LOGIT(x1,q1) EDGE_LOGIT(x2,q2) EDGE_LOGIT(x3,q3)
        float nm = fmaxf(m, fmaxf(fmaxf(q0,q1),fmaxf(q2,q3)));
        float sc = __expf(m-nm);
        float e0 = __expf(q0-nm), e1 = __expf(q1-nm);
        float e2 = __expf(q2-nm), e3 = __expf(q3-nm);
        ls = fmaf(ls, sc, (e0+e1)+(e2+e3));
        acc.x = fmaf(acc.x, sc, fmaf(e0,x0.x, fmaf(e1,x1.x, fmaf(e2,x2.x, e3*x3.x))));
        acc.y = fmaf(acc.y, sc, fmaf(e0,x0.y, fmaf(e1,x1.y, fmaf(e2,x2.y, e3*x3.y))));
        acc.z = fmaf(acc.z, sc, fmaf(e0,x0.z, fmaf(e1,x1.z, fmaf(e2,x2.z, e3*x3.z))));
        acc.w = fmaf(acc.w, sc, fmaf(e0,x0.w, fmaf(e1,x1.w, fmaf(e2,x2.w, e3*x3.w))));
        m = nm;
    }
    #pragma unroll
    for(int i=0;i<4;i++){
        int idx = base + 2*i + half;
        if(idx < end){
            int j = colidx[idx];
            float4 xj; LOADX(j, xj)
            float q; EDGE_LOGIT(xj, q)
            float nm = fmaxf(m, q);
            float sc = __expf(m-nm);
            float p  = __expf(q-nm);
            ls = fmaf(ls, sc, p);
            acc.x = fmaf(acc.x, sc, p*xj.x);
            acc.y = fmaf(acc.y, sc, p*xj.y);
            acc.z = fmaf(acc.z, sc, p*xj.z);
            acc.w = fmaf(acc.w, sc, p*xj.w);
            m = nm;
        }
    }
    #undef EDGE_LOGIT
    #undef LOADX

    {   // merge the two half-wave softmax states
        float mo  = __shfl_xor(m, 32);
        float lso = __shfl_xor(ls, 32);
        float4 ao;
        ao.x = __shfl_xor(acc.x,32); ao.y = __shfl_xor(acc.y,32);
        ao.z = __shfl_xor(acc.z,32); ao.w = __shfl_xor(acc.w,32);
        float nm = fmaxf(m, mo);
        float s0 = __expf(m-nm), s1 = __expf(mo-nm);
        ls = ls*s0 + lso*s1;
        acc.x = acc.x*s0 + ao.x*s1;
        acc.y = acc.y*s0 + ao.y*s1;
        acc.z = acc.z*s0 + ao.z*s1;
        acc.w = acc.w*s0 + ao.w*s1;
    }

    float inv = 1.0f/ls;
    float4 bo4 = *(const float4*)(bo + c4);
    float o0 = fmaf(acc.x,inv,bo4.x), o1 = fmaf(acc.y,inv,bo4.y);
    float o2 = fmaf(acc.z,inv,bo4.z), o3 = fmaf(acc.w,inv,bo4.w);
    float s1v = (o0+o1)+(o2+o3);
    float s2v = fmaf(o0,o0, fmaf(o1,o1, fmaf(o2,o2, o3*o3)));
    #pragma unroll
    for(int msk=1;msk<32;msk<<=1){ s1v += __shfl_xor(s1v,msk); s2v += __shfl_xor(s2v,msk); }
    float mean = s1v*(1.f/128.f);
    float var  = s2v*(1.f/128.f) - mean*mean;
    float rstd = rsqrtf(var + 1e-5f);
    float4 g4  = *(const float4*)(gg + c4);
    float4 be4 = *(const float4*)(be + c4);
    float r0 = gelu_f(fmaf(g4.x*(o0-mean), rstd, be4.x));
    float r1 = gelu_f(fmaf(g4.y*(o1-mean), rstd, be4.y));
    float r2 = gelu_f(fmaf(g4.z*(o2-mean), rstd, be4.z));
    float r3 = gelu_f(fmaf(g4.w*(o3-mean), rstd, be4.w));
    if(hold){
        float4 hv = *(const float4*)(hold + (size_t)node*HC_DIM + c4);
        r0 += hv.x; r1 += hv.y; r2 += hv.z; r3 += hv.w;
    }
    if(half==0){
        *(float4*)(hout + (size_t)node*HC_DIM + c4) = make_float4(r0,r1,r2,r3);
        short4v vh, vl; short hh, ll;
        split2(r0,hh,ll); vh[0]=hh; vl[0]=ll;
        split2(r1,hh,ll); vh[1]=hh; vl[1]=ll;
        split2(r2,hh,ll); vh[2]=hh; vl[2]=ll;
        split2(r3,hh,ll); vh[3]=hh; vl[3]=ll;
        *(short4v*)(hi_out + (size_t)node*HC_DIM + c4) = vh;
        *(short4v*)(lo_out + (size_t)node*HC_DIM + c4) = vl;
    }
}

extern "C" void kernel_launch(void* const* d_in, const int* in_sizes, int n_in,
                              void* d_out, int out_size, void* d_ws, size_t ws_size,
                              hipStream_t stream)
{
    const float* x   = (const float*)d_in[0];
    const int*   ei  = (const int*)  d_in[1];
    const float* Win = (const float*)d_in[2];
    const float* bin = (const float*)d_in[3];
    const float *Wl[3], *bl[3], *Wr[3], *br[3], *att[3], *bo[3], *gg[3], *be[3];
    for(int i=0;i<3;i++){
        const int base = 4 + 8*i;
        Wl[i]=(const float*)d_in[base+0]; bl[i]=(const float*)d_in[base+1];
        Wr[i]=(const float*)d_in[base+2]; br[i]=(const float*)d_in[base+3];
        att[i]=(const float*)d_in[base+4]; bo[i]=(const float*)d_in[base+5];
        gg[i]=(const float*)d_in[base+6]; be[i]=(const float*)d_in[base+7];
    }
    const float* Wout=(const float*)d_in[28];
    const float* bout=(const float*)d_in[29];
    float* out = (float*)d_out;

    char* w = (char*)d_ws;
    float* hA = (float*)w;  w += (size_t)N_NODES*HC_DIM*4;
    float* hB = (float*)w;  w += (size_t)N_NODES*HC_DIM*4;
    float* XL = (float*)w;  w += (size_t)N_NODES*HC_DIM*4;
    unsigned short* XR16 = (unsigned short*)w; w += (size_t)N_NODES*HC_DIM*2;
    short* hAhi = (short*)w; w += (size_t)N_NODES*HC_DIM*2;
    short* hAlo = (short*)w; w += (size_t)N_NODES*HC_DIM*2;
    short* hBhi = (short*)w; w += (size_t)N_NODES*HC_DIM*2;
    short* hBlo = (short*)w; w += (size_t)N_NODES*HC_DIM*2;
    short* WT   = (short*)w; w += (size_t)180224*2;
    int* rowptr = (int*)w;  w += (size_t)(N_NODES+2)*4;
    int* cursor = (int*)w;  w += (size_t)N_NODES*4;
    int* colidx = (int*)w;  w += (size_t)N_EDGES*4;
    int* part   = (int*)w;  w += 256*4;

    const short* WTl0 = WT + 0;      const short* WTr0 = WT + 8192;
    const short* WTl1 = WT + 16384;  const short* WTr1 = WT + 49152;
    const short* WTl2 = WT + 81920;  const short* WTr2 = WT + 114688;
    const short* WTo  = WT + 147456;

    // ---- one cooperative setup dispatch: splitW + zero + input-proj + CSR ----
    SetupArgs sa;
    sa.x = x; sa.Win = Win; sa.bin = bin;
    sa.h = hA; sa.hhi = hAhi; sa.hlo = hAlo;
    sa.src = ei; sa.dst = ei + N_EDGES;
    sa.cursor = cursor; sa.rowptr = rowptr; sa.part = part; sa.colidx = colidx;
    sa.W[0]=Wl[0]; sa.W[1]=Wr[0]; sa.W[2]=Wl[1]; sa.W[3]=Wr[1];
    sa.W[4]=Wl[2]; sa.W[5]=Wr[2]; sa.W[6]=Wout;
    sa.WT = WT;
    void* kargs[] = { (void*)&sa };
    hipLaunchCooperativeKernel((void*)k_setup, dim3(COOP_NB), dim3(256), kargs, 0, stream);

    // ---- layer 0: hA[N,32] -> hB[N,128] (no residual) ----
    k_mfma<32,true,false><<<782,256,0,stream>>>(hAhi, hAlo, WTl0, bl[0], WTr0, br[0], XL, XR16);
    k_node<<<12500,256,0,stream>>>(XL,XR16,rowptr,colidx,att[0],bo[0],gg[0],be[0],
                                   (const float*)nullptr, hB, hBhi, hBlo);

    // ---- layer 1: hB -> hA (residual hB) ----
    k_mfma<128,true,false><<<782,256,0,stream>>>(hBhi, hBlo, WTl1, bl[1], WTr1, br[1], XL, XR16);
    k_node<<<12500,256,0,stream>>>(XL,XR16,rowptr,colidx,att[1],bo[1],gg[1],be[1], hB, hA, hAhi, hAlo);

    // ---- layer 2: hA -> hB (residual hA) ----
    k_mfma<128,true,false><<<782,256,0,stream>>>(hAhi, hAlo, WTl2, bl[2], WTr2, br[2], XL, XR16);
    k_node<<<12500,256,0,stream>>>(XL,XR16,rowptr,colidx,att[2],bo[2],gg[2],be[2], hA, hB, hBhi, hBlo);

    // ---- output projection + fused row L2-normalize -> out ----
    k_mfma<128,false,true><<<782,256,0,stream>>>(hBhi, hBlo, WTo, bout, nullptr, nullptr, out, nullptr);
}

// Round 9
// 515.940 us; speedup vs baseline: 1.6024x; 1.6024x over previous
//
#include <hip/hip_runtime.h>
#include <hip/hip_bf16.h>
#include <math.h>

#define N_NODES 50000
#define N_EDGES 800000
#define IN_DIM  128
#define HC_DIM  128
#define HID_C   32
#define SCAN_NB 196   // ceil(50000/256)

typedef __attribute__((ext_vector_type(8))) short short8;   // 8 bf16 = 4 VGPR (MFMA A/B frag)
typedef __attribute__((ext_vector_type(4))) short short4v;
typedef __attribute__((ext_vector_type(4))) float f32x4;    // MFMA C/D frag

__device__ __forceinline__ float gelu_f(float x){
    return 0.5f*x*(1.0f + erff(x*0.7071067811865475f));
}

// fp32 -> (hi, lo) bf16 split: hi = rn(f), lo = rn(f - hi). hi*hi+hi*lo+lo*hi ~ fp32.
__device__ __forceinline__ void split2(float f, short& h, short& l){
    __hip_bfloat16 bh = __float2bfloat16(f);
    float r = f - __bfloat162float(bh);
    __hip_bfloat16 blo = __float2bfloat16(r);
    h = *reinterpret_cast<short*>(&bh);
    l = *reinterpret_cast<short*>(&blo);
}
__device__ __forceinline__ unsigned short f2bf(float f){
    __hip_bfloat16 b = __float2bfloat16(f);
    return *reinterpret_cast<unsigned short*>(&b);
}
__device__ __forceinline__ float bf2f(unsigned short u){
    return __uint_as_float(((unsigned)u)<<16);
}

// ---------------- CSR build (separate small dispatches — r8 showed coop-kernel
// grid.sync costs 450us; stream-ordered 3-5us dispatches win by 30x) ----------------
__global__ __launch_bounds__(256) void k_count(const int* __restrict__ dst, int* __restrict__ cnt){
    int e = blockIdx.x*256 + threadIdx.x;
    if(e<N_EDGES) atomicAdd(&cnt[dst[e]], 1);
}

__global__ __launch_bounds__(256) void k_scan1(const int* __restrict__ cnt, int* __restrict__ rowptr,
                                               int* __restrict__ part){
    __shared__ int sh[256];
    int t=threadIdx.x; int i=blockIdx.x*256+t;
    int v = (i<N_NODES)? cnt[i] : 0;
    sh[t]=v; __syncthreads();
    for(int off=1; off<256; off<<=1){
        int y = (t>=off)? sh[t-off] : 0;
        __syncthreads();
        sh[t] += y;
        __syncthreads();
    }
    if(i<N_NODES) rowptr[i] = sh[t]-v;
    if(t==255) part[blockIdx.x] = sh[255];
}

__global__ __launch_bounds__(256) void k_scan2(int* __restrict__ part){
    __shared__ int sh[256];
    int t=threadIdx.x;
    int v = (t<SCAN_NB)? part[t] : 0;
    sh[t]=v; __syncthreads();
    for(int off=1; off<256; off<<=1){
        int y=(t>=off)? sh[t-off]:0;
        __syncthreads();
        sh[t]+=y;
        __syncthreads();
    }
    if(t<SCAN_NB) part[t] = sh[t]-v;
}

__global__ __launch_bounds__(256) void k_scan3(int* __restrict__ rowptr, const int* __restrict__ part,
                                               int* __restrict__ cur){
    int t=threadIdx.x; int i=blockIdx.x*256+t;
    if(i<N_NODES){
        int v = rowptr[i] + part[blockIdx.x];
        rowptr[i]=v; cur[i]=v;
    }
    if(i==0) rowptr[N_NODES]=N_EDGES;
}

__global__ __launch_bounds__(256) void k_fill(const int* __restrict__ src, const int* __restrict__ dst,
                                              int* __restrict__ cur, int* __restrict__ col){
    int e = blockIdx.x*256+threadIdx.x;
    if(e<N_EDGES){
        int d = dst[e];
        int p = atomicAdd(&cur[d],1);
        col[p] = src[e];
    }
}

// Pre-split all 7 weight matrices into transposed hi/lo bf16 [n][k].
// WT offsets (shorts): m0@0(K32) m1@8192(K32) m2@16384 m3@49152 m4@81920 m5@114688 m6@147456
__global__ __launch_bounds__(256) void k_splitW(const float* __restrict__ W0, const float* __restrict__ W1,
                                                const float* __restrict__ W2, const float* __restrict__ W3,
                                                const float* __restrict__ W4, const float* __restrict__ W5,
                                                const float* __restrict__ W6, short* __restrict__ WT){
    int bx = blockIdx.x;
    int m, kc;
    if(bx < 2){ m = bx; kc = 0; }
    else { m = 2 + (bx-2)/4; kc = (bx-2)&3; }
    const float* src; int K; size_t off;
    switch(m){
        case 0: src=W0; K=32;  off=0;      break;
        case 1: src=W1; K=32;  off=8192;   break;
        case 2: src=W2; K=128; off=16384;  break;
        case 3: src=W3; K=128; off=49152;  break;
        case 4: src=W4; K=128; off=81920;  break;
        case 5: src=W5; K=128; off=114688; break;
        default:src=W6; K=128; off=147456; break;
    }
    short* hi = WT + off;
    short* lo = hi + (size_t)K*HC_DIM;
    #pragma unroll
    for(int i=0;i<16;i++){
        int idx = threadIdx.x + i*256;
        int k = kc*32 + (idx>>7);
        int n = idx & 127;
        float f = src[(size_t)k*HC_DIM + n];
        short h,l; split2(f,h,l);
        hi[(size_t)n*K + k] = h;
        lo[(size_t)n*K + k] = l;
    }
}

// h[N,32] = gelu(x[N,128] @ Win[128,32] + bin); also emits bf16 hi/lo copies.
__global__ __launch_bounds__(256) void k_gemm_in(const float* __restrict__ x, const float* __restrict__ W,
                                                 const float* __restrict__ b, float* __restrict__ h,
                                                 short* __restrict__ hhi, short* __restrict__ hlo){
    int id = blockIdx.x*256+threadIdx.x;
    int r = id>>5, c = id&31;
    const float4* x4 = (const float4*)(x + (size_t)r*IN_DIM);
    float acc=0.f;
    #pragma unroll 8
    for(int k=0;k<IN_DIM/4;k++){
        float4 xv = x4[k];
        acc = fmaf(xv.x, W[(4*k  )*HID_C+c], acc);
        acc = fmaf(xv.y, W[(4*k+1)*HID_C+c], acc);
        acc = fmaf(xv.z, W[(4*k+2)*HID_C+c], acc);
        acc = fmaf(xv.w, W[(4*k+3)*HID_C+c], acc);
    }
    float v = gelu_f(acc + b[c]);
    h[(size_t)r*HID_C+c] = v;
    short hh,ll; split2(v,hh,ll);
    hhi[(size_t)r*HID_C+c] = hh;
    hlo[(size_t)r*HID_C+c] = ll;
}

// ---------------- full-width MFMA GEMM (bf16x3, ~fp32) ----------------
// C[64 rows x 128 cols] = A@W (+pair). Block 256 thr = 4 waves; wave w owns
// n-subtiles {w*16, 64+w*16}; 4 m-tiles of 16 rows; per K-chunk(32):
// 16 ds_read_b128 : 48 MFMA (PAIR). A-frag A[m=lane&15][k=quad*8+j];
// B-frag from WT[n][k]; C/D col=lane&15, row=quad*4+reg (verified r6-r8).
// NORM variant fuses bias + row-L2-normalize, writes final out directly.
// PAIR variant writes XR as bf16 (k_node gathers in bf16 — verified r8, absmax 2e-3).
template<int K, bool PAIR, bool NORM>
__global__ __launch_bounds__(256) void k_mfma(const short* __restrict__ Ahi, const short* __restrict__ Alo,
                                              const short* __restrict__ WTl, const float* __restrict__ bl,
                                              const short* __restrict__ WTr, const float* __restrict__ br,
                                              float* __restrict__ XL, unsigned short* __restrict__ XR16){
    constexpr int LDS_K = 40;          // 32 + 8 pad shorts (80B rows)
    constexpr int NCH = K / 32;
    __shared__ short As_hi[64*LDS_K], As_lo[64*LDS_K];
    __shared__ short Bh0[128*LDS_K], Bl0[128*LDS_K];
    __shared__ short Bh1[PAIR?128*LDS_K:1], Bl1[PAIR?128*LDS_K:1];
    __shared__ float ssq[NORM?256:1];

    int t = threadIdx.x;
    int lane = t & 63, wave = t >> 6;
    int quad = lane >> 4, ml = lane & 15;
    int rbase = blockIdx.x * 64;

    const short* WTl_lo = WTl + (size_t)K*HC_DIM;
    const short* WTr_lo = PAIR ? (WTr + (size_t)K*HC_DIM) : nullptr;

    f32x4 accL[4][2], accR[4][2];
    #pragma unroll
    for(int i=0;i<4;i++)
        #pragma unroll
        for(int j=0;j<2;j++){ accL[i][j]=(f32x4){0,0,0,0}; accR[i][j]=(f32x4){0,0,0,0}; }

    int r = t >> 2, seg = t & 3;
    int gr = rbase + r; if(gr >= N_NODES) gr = N_NODES-1;

    for(int c=0; c<NCH; c++){
        if(c) __syncthreads();
        size_t ka = (size_t)gr*K + c*32 + seg*8;
        *(short8*)(As_hi + r*LDS_K + seg*8) = *(const short8*)(Ahi + ka);
        *(short8*)(As_lo + r*LDS_K + seg*8) = *(const short8*)(Alo + ka);
        #pragma unroll
        for(int u=0; u<2; u++){
            int uu = t + u*256;
            int n = uu >> 2, sg = uu & 3;
            size_t kw = (size_t)n*K + c*32 + sg*8;
            *(short8*)(Bh0 + n*LDS_K + sg*8) = *(const short8*)(WTl + kw);
            *(short8*)(Bl0 + n*LDS_K + sg*8) = *(const short8*)(WTl_lo + kw);
            if(PAIR){
                *(short8*)(Bh1 + n*LDS_K + sg*8) = *(const short8*)(WTr + kw);
                *(short8*)(Bl1 + n*LDS_K + sg*8) = *(const short8*)(WTr_lo + kw);
            }
        }
        __syncthreads();

        int k0 = quad*8;
        short8 ah[4], al[4];
        #pragma unroll
        for(int i=0;i<4;i++){
            ah[i] = *(const short8*)(As_hi + (16*i + ml)*LDS_K + k0);
            al[i] = *(const short8*)(As_lo + (16*i + ml)*LDS_K + k0);
        }
        #pragma unroll
        for(int j=0;j<2;j++){
            int nrow = j*64 + wave*16 + ml;
            short8 bh = *(const short8*)(Bh0 + nrow*LDS_K + k0);
            short8 blo = *(const short8*)(Bl0 + nrow*LDS_K + k0);
            #pragma unroll
            for(int i=0;i<4;i++){
                accL[i][j] = __builtin_amdgcn_mfma_f32_16x16x32_bf16(ah[i], bh,  accL[i][j], 0,0,0);
                accL[i][j] = __builtin_amdgcn_mfma_f32_16x16x32_bf16(ah[i], blo, accL[i][j], 0,0,0);
                accL[i][j] = __builtin_amdgcn_mfma_f32_16x16x32_bf16(al[i], bh,  accL[i][j], 0,0,0);
            }
            if(PAIR){
                short8 ch = *(const short8*)(Bh1 + nrow*LDS_K + k0);
                short8 cl = *(const short8*)(Bl1 + nrow*LDS_K + k0);
                #pragma unroll
                for(int i=0;i<4;i++){
                    accR[i][j] = __builtin_amdgcn_mfma_f32_16x16x32_bf16(ah[i], ch, accR[i][j], 0,0,0);
                    accR[i][j] = __builtin_amdgcn_mfma_f32_16x16x32_bf16(ah[i], cl, accR[i][j], 0,0,0);
                    accR[i][j] = __builtin_amdgcn_mfma_f32_16x16x32_bf16(al[i], ch, accR[i][j], 0,0,0);
                }
            }
        }
    }

    int col0 = wave*16 + ml, col1 = 64 + wave*16 + ml;
    float bL0 = bl[col0], bL1 = bl[col1];

    if(NORM){
        #pragma unroll
        for(int i=0;i<4;i++){
            #pragma unroll
            for(int rr=0;rr<4;rr++){
                float v0 = accL[i][0][rr] + bL0;
                float v1 = accL[i][1][rr] + bL1;
                float p = v0*v0 + v1*v1;
                p += __shfl_xor(p,1); p += __shfl_xor(p,2);
                p += __shfl_xor(p,4); p += __shfl_xor(p,8);
                if(ml==0) ssq[wave*64 + 16*i + quad*4 + rr] = p;
            }
        }
        __syncthreads();
        #pragma unroll
        for(int i=0;i<4;i++){
            #pragma unroll
            for(int rr=0;rr<4;rr++){
                int row = 16*i + quad*4 + rr;
                int grr = rbase + row;
                if(grr < N_NODES){
                    float tot = ssq[row] + ssq[64+row] + ssq[128+row] + ssq[192+row];
                    float inv = 1.0f / fmaxf(sqrtf(tot), 1e-12f);
                    XL[(size_t)grr*HC_DIM + col0] = (accL[i][0][rr] + bL0) * inv;
                    XL[(size_t)grr*HC_DIM + col1] = (accL[i][1][rr] + bL1) * inv;
                }
            }
        }
    } else {
        float bR0 = PAIR ? br[col0] : 0.f, bR1 = PAIR ? br[col1] : 0.f;
        #pragma unroll
        for(int i=0;i<4;i++){
            #pragma unroll
            for(int rr=0;rr<4;rr++){
                int grr = rbase + 16*i + quad*4 + rr;
                if(grr < N_NODES){
                    XL[(size_t)grr*HC_DIM + col0] = accL[i][0][rr] + bL0;
                    XL[(size_t)grr*HC_DIM + col1] = accL[i][1][rr] + bL1;
                    if(PAIR){
                        XR16[(size_t)grr*HC_DIM + col0] = f2bf(accR[i][0][rr] + bR0);
                        XR16[(size_t)grr*HC_DIM + col1] = f2bf(accR[i][1][rr] + bR1);
                    }
                }
            }
        }
    }
}

// ---------------- fused per-node GATv2 (XR in bf16) ----------------
// one wave per node; cg = lane&31 owns channels [4cg..4cg+4), half = lane>>5 owns
// alternate edges; 3-shfl head-dot over 8 lanes serves 2 edges/inst. Epilogue:
// bias + LayerNorm + GELU + residual, emits fp32 h + bf16 hi/lo for next GEMM.
__global__ __launch_bounds__(256) void k_node(const float* __restrict__ XL, const unsigned short* __restrict__ XR,
    const int* __restrict__ rowptr, const int* __restrict__ colidx,
    const float* __restrict__ att, const float* __restrict__ bo,
    const float* __restrict__ gg, const float* __restrict__ be,
    const float* __restrict__ hold, float* __restrict__ hout,
    short* __restrict__ hi_out, short* __restrict__ lo_out)
{
    int wave=threadIdx.x>>6, lane=threadIdx.x&63;
    int node = blockIdx.x*4+wave;
    int cg = lane & 31, half = lane >> 5;
    int c4 = cg << 2;

    float4 xl = *(const float4*)(XL + (size_t)node*HC_DIM + c4);
    float4 av = *(const float4*)(att + c4);
    int beg = rowptr[node], end = rowptr[node+1];

    #define LOADX(j, xx) { ushort4 u_ = *(const ushort4*)(XR + (size_t)(j)*HC_DIM + c4); \
        xx = make_float4(bf2f(u_.x), bf2f(u_.y), bf2f(u_.z), bf2f(u_.w)); }
    #define EDGE_LOGIT(xj, q) { \
        float u0 = xl.x + xj.x; u0 = (u0>0.f)?u0:0.2f*u0; \
        float u1 = xl.y + xj.y; u1 = (u1>0.f)?u1:0.2f*u1; \
        float u2 = xl.z + xj.z; u2 = (u2>0.f)?u2:0.2f*u2; \
        float u3 = xl.w + xj.w; u3 = (u3>0.f)?u3:0.2f*u3; \
        q = fmaf(u0,av.x, fmaf(u1,av.y, fmaf(u2,av.z, u3*av.w))); \
        q += __shfl_xor(q,1); q += __shfl_xor(q,2); q += __shfl_xor(q,4); }

    float4 xs; LOADX(node, xs)
    float qs; EDGE_LOGIT(xs, qs)
    float m, ls; float4 acc;
    if(half==0){ m = qs; ls = 1.f; acc = xs; }
    else       { m = -INFINITY; ls = 0.f; acc = make_float4(0.f,0.f,0.f,0.f); }

    int P = end - beg;
    int nb = P >> 3;
    int base = beg;
    for(int b=0; b<nb; b++, base += 8){
        int j0 = colidx[base     + half];
        int j1 = colidx[base + 2 + half];
        int j2 = colidx[base + 4 + half];
        int j3 = colidx[base + 6 + half];
        float4 x0, x1, x2, x3;
        LOADX(j0, x0) LOADX(j1, x1) LOADX(j2, x2) LOADX(j3, x3)
        float q0,q1,q2,q3;
        EDGE_LOGIT(x0,q0) EDGE_LOGIT(x1,q1) EDGE_LOGIT(x2,q2) EDGE_LOGIT(x3,q3)
        float nm = fmaxf(m, fmaxf(fmaxf(q0,q1),fmaxf(q2,q3)));
        float sc = __expf(m-nm);
        float e0 = __expf(q0-nm), e1 = __expf(q1-nm);
        float e2 = __expf(q2-nm), e3 = __expf(q3-nm);
        ls = fmaf(ls, sc, (e0+e1)+(e2+e3));
        acc.x = fmaf(acc.x, sc, fmaf(e0,x0.x, fmaf(e1,x1.x, fmaf(e2,x2.x, e3*x3.x))));
        acc.y = fmaf(acc.y, sc, fmaf(e0,x0.y, fmaf(e1,x1.y, fmaf(e2,x2.y, e3*x3.y))));
        acc.z = fmaf(acc.z, sc, fmaf(e0,x0.z, fmaf(e1,x1.z, fmaf(e2,x2.z, e3*x3.z))));
        acc.w = fmaf(acc.w, sc, fmaf(e0,x0.w, fmaf(e1,x1.w, fmaf(e2,x2.w, e3*x3.w))));
        m = nm;
    }
    #pragma unroll
    for(int i=0;i<4;i++){
        int idx = base + 2*i + half;
        if(idx < end){
            int j = colidx[idx];
            float4 xj; LOADX(j, xj)
            float q; EDGE_LOGIT(xj, q)
            float nm = fmaxf(m, q);
            float sc = __expf(m-nm);
            float p  = __expf(q-nm);
            ls = fmaf(ls, sc, p);
            acc.x = fmaf(acc.x, sc, p*xj.x);
            acc.y = fmaf(acc.y, sc, p*xj.y);
            acc.z = fmaf(acc.z, sc, p*xj.z);
            acc.w = fmaf(acc.w, sc, p*xj.w);
            m = nm;
        }
    }
    #undef EDGE_LOGIT
    #undef LOADX

    {   // merge the two half-wave softmax states
        float mo  = __shfl_xor(m, 32);
        float lso = __shfl_xor(ls, 32);
        float4 ao;
        ao.x = __shfl_xor(acc.x,32); ao.y = __shfl_xor(acc.y,32);
        ao.z = __shfl_xor(acc.z,32); ao.w = __shfl_xor(acc.w,32);
        float nm = fmaxf(m, mo);
        float s0 = __expf(m-nm), s1 = __expf(mo-nm);
        ls = ls*s0 + lso*s1;
        acc.x = acc.x*s0 + ao.x*s1;
        acc.y = acc.y*s0 + ao.y*s1;
        acc.z = acc.z*s0 + ao.z*s1;
        acc.w = acc.w*s0 + ao.w*s1;
    }

    float inv = 1.0f/ls;
    float4 bo4 = *(const float4*)(bo + c4);
    float o0 = fmaf(acc.x,inv,bo4.x), o1 = fmaf(acc.y,inv,bo4.y);
    float o2 = fmaf(acc.z,inv,bo4.z), o3 = fmaf(acc.w,inv,bo4.w);
    float s1v = (o0+o1)+(o2+o3);
    float s2v = fmaf(o0,o0, fmaf(o1,o1, fmaf(o2,o2, o3*o3)));
    #pragma unroll
    for(int msk=1;msk<32;msk<<=1){ s1v += __shfl_xor(s1v,msk); s2v += __shfl_xor(s2v,msk); }
    float mean = s1v*(1.f/128.f);
    float var  = s2v*(1.f/128.f) - mean*mean;
    float rstd = rsqrtf(var + 1e-5f);
    float4 g4  = *(const float4*)(gg + c4);
    float4 be4 = *(const float4*)(be + c4);
    float r0 = gelu_f(fmaf(g4.x*(o0-mean), rstd, be4.x));
    float r1 = gelu_f(fmaf(g4.y*(o1-mean), rstd, be4.y));
    float r2 = gelu_f(fmaf(g4.z*(o2-mean), rstd, be4.z));
    float r3 = gelu_f(fmaf(g4.w*(o3-mean), rstd, be4.w));
    if(hold){
        float4 hv = *(const float4*)(hold + (size_t)node*HC_DIM + c4);
        r0 += hv.x; r1 += hv.y; r2 += hv.z; r3 += hv.w;
    }
    if(half==0){
        *(float4*)(hout + (size_t)node*HC_DIM + c4) = make_float4(r0,r1,r2,r3);
        short4v vh, vl; short hh, ll;
        split2(r0,hh,ll); vh[0]=hh; vl[0]=ll;
        split2(r1,hh,ll); vh[1]=hh; vl[1]=ll;
        split2(r2,hh,ll); vh[2]=hh; vl[2]=ll;
        split2(r3,hh,ll); vh[3]=hh; vl[3]=ll;
        *(short4v*)(hi_out + (size_t)node*HC_DIM + c4) = vh;
        *(short4v*)(lo_out + (size_t)node*HC_DIM + c4) = vl;
    }
}

extern "C" void kernel_launch(void* const* d_in, const int* in_sizes, int n_in,
                              void* d_out, int out_size, void* d_ws, size_t ws_size,
                              hipStream_t stream)
{
    const float* x   = (const float*)d_in[0];
    const int*   ei  = (const int*)  d_in[1];
    const float* Win = (const float*)d_in[2];
    const float* bin = (const float*)d_in[3];
    const float *Wl[3], *bl[3], *Wr[3], *br[3], *att[3], *bo[3], *gg[3], *be[3];
    for(int i=0;i<3;i++){
        const int base = 4 + 8*i;
        Wl[i]=(const float*)d_in[base+0]; bl[i]=(const float*)d_in[base+1];
        Wr[i]=(const float*)d_in[base+2]; br[i]=(const float*)d_in[base+3];
        att[i]=(const float*)d_in[base+4]; bo[i]=(const float*)d_in[base+5];
        gg[i]=(const float*)d_in[base+6]; be[i]=(const float*)d_in[base+7];
    }
    const float* Wout=(const float*)d_in[28];
    const float* bout=(const float*)d_in[29];
    float* out = (float*)d_out;

    char* w = (char*)d_ws;
    float* hA = (float*)w;  w += (size_t)N_NODES*HC_DIM*4;
    float* hB = (float*)w;  w += (size_t)N_NODES*HC_DIM*4;
    float* XL = (float*)w;  w += (size_t)N_NODES*HC_DIM*4;
    unsigned short* XR16 = (unsigned short*)w; w += (size_t)N_NODES*HC_DIM*2;
    short* hAhi = (short*)w; w += (size_t)N_NODES*HC_DIM*2;
    short* hAlo = (short*)w; w += (size_t)N_NODES*HC_DIM*2;
    short* hBhi = (short*)w; w += (size_t)N_NODES*HC_DIM*2;
    short* hBlo = (short*)w; w += (size_t)N_NODES*HC_DIM*2;
    short* WT   = (short*)w; w += (size_t)180224*2;
    int* rowptr = (int*)w;  w += (size_t)(N_NODES+2)*4;
    int* cursor = (int*)w;  w += (size_t)N_NODES*4;
    int* colidx = (int*)w;  w += (size_t)N_EDGES*4;
    int* part   = (int*)w;  w += 256*4;

    const int* srcp = ei;
    const int* dstp = ei + N_EDGES;

    const short* WTl0 = WT + 0;      const short* WTr0 = WT + 8192;
    const short* WTl1 = WT + 16384;  const short* WTr1 = WT + 49152;
    const short* WTl2 = WT + 81920;  const short* WTr2 = WT + 114688;
    const short* WTo  = WT + 147456;

    // ---- weight split + CSR build + input projection (small stream-ordered dispatches) ----
    k_splitW<<<22,256,0,stream>>>(Wl[0],Wr[0],Wl[1],Wr[1],Wl[2],Wr[2],Wout, WT);
    hipMemsetAsync(cursor, 0, (size_t)N_NODES*4, stream);
    k_count <<<3125,256, 0, stream>>>(dstp, cursor);
    k_scan1 <<<SCAN_NB,256,0,stream>>>(cursor, rowptr, part);
    k_scan2 <<<1,   256, 0, stream>>>(part);
    k_scan3 <<<SCAN_NB,256,0,stream>>>(rowptr, part, cursor);
    k_fill  <<<3125,256, 0, stream>>>(srcp, dstp, cursor, colidx);
    k_gemm_in<<<6250,256,0,stream>>>(x, Win, bin, hA, hAhi, hAlo);

    // ---- layer 0: hA[N,32] -> hB[N,128] (no residual) ----
    k_mfma<32,true,false><<<782,256,0,stream>>>(hAhi, hAlo, WTl0, bl[0], WTr0, br[0], XL, XR16);
    k_node<<<12500,256,0,stream>>>(XL,XR16,rowptr,colidx,att[0],bo[0],gg[0],be[0],
                                   (const float*)nullptr, hB, hBhi, hBlo);

    // ---- layer 1: hB -> hA (residual hB) ----
    k_mfma<128,true,false><<<782,256,0,stream>>>(hBhi, hBlo, WTl1, bl[1], WTr1, br[1], XL, XR16);
    k_node<<<12500,256,0,stream>>>(XL,XR16,rowptr,colidx,att[1],bo[1],gg[1],be[1], hB, hA, hAhi, hAlo);

    // ---- layer 2: hA -> hB (residual hA) ----
    k_mfma<128,true,false><<<782,256,0,stream>>>(hAhi, hAlo, WTl2, bl[2], WTr2, br[2], XL, XR16);
    k_node<<<12500,256,0,stream>>>(XL,XR16,rowptr,colidx,att[2],bo[2],gg[2],be[2], hA, hB, hBhi, hBlo);

    // ---- output projection + fused row L2-normalize -> out ----
    k_mfma<128,false,true><<<782,256,0,stream>>>(hBhi, hBlo, WTo, bout, nullptr, nullptr, out, nullptr);
}

// Round 10
// 500.268 us; speedup vs baseline: 1.6526x; 1.0313x over previous
//
#include <hip/hip_runtime.h>
#include <hip/hip_bf16.h>
#include <math.h>

#define N_NODES 50000
#define N_EDGES 800000
#define IN_DIM  128
#define HC_DIM  128
#define HID_C   32
#define SCAN_NB 196   // ceil(50000/256)
#define LOG2E   1.4426950408889634f

typedef __attribute__((ext_vector_type(8))) short short8;   // 8 bf16 = 4 VGPR (MFMA A/B frag)
typedef __attribute__((ext_vector_type(4))) short short4v;
typedef __attribute__((ext_vector_type(4))) float f32x4;    // MFMA C/D frag

__device__ __forceinline__ float gelu_f(float x){
    return 0.5f*x*(1.0f + erff(x*0.7071067811865475f));
}

// fp32 -> (hi, lo) bf16 split: hi = rn(f), lo = rn(f - hi). hi*hi+hi*lo+lo*hi ~ fp32.
__device__ __forceinline__ void split2(float f, short& h, short& l){
    __hip_bfloat16 bh = __float2bfloat16(f);
    float r = f - __bfloat162float(bh);
    __hip_bfloat16 blo = __float2bfloat16(r);
    h = *reinterpret_cast<short*>(&bh);
    l = *reinterpret_cast<short*>(&blo);
}
__device__ __forceinline__ unsigned short f2bf(float f){
    __hip_bfloat16 b = __float2bfloat16(f);
    return *reinterpret_cast<unsigned short*>(&b);
}
__device__ __forceinline__ float bf2f(unsigned short u){
    return __uint_as_float(((unsigned)u)<<16);
}

// ---------------- CSR build ----------------
// r9: k_fill's atomic-return chain was 63us at 0.3% VALU. Rank-trick: count's
// atomicAdd return IS the within-node rank -> store it; fill becomes a pure
// scatter with no atomics. Both kernels 4 edges/thread (coalesced strided) for MLP.
__global__ __launch_bounds__(256) void k_count(const int* __restrict__ dst, int* __restrict__ cnt,
                                               int* __restrict__ rank){
    int b = blockIdx.x*1024 + threadIdx.x;
    #pragma unroll
    for(int i=0;i<4;i++){
        int e = b + i*256;
        if(e < N_EDGES) rank[e] = atomicAdd(&cnt[dst[e]], 1);
    }
}

__global__ __launch_bounds__(256) void k_scan1(const int* __restrict__ cnt, int* __restrict__ rowptr,
                                               int* __restrict__ part){
    __shared__ int sh[256];
    int t=threadIdx.x; int i=blockIdx.x*256+t;
    int v = (i<N_NODES)? cnt[i] : 0;
    sh[t]=v; __syncthreads();
    for(int off=1; off<256; off<<=1){
        int y = (t>=off)? sh[t-off] : 0;
        __syncthreads();
        sh[t] += y;
        __syncthreads();
    }
    if(i<N_NODES) rowptr[i] = sh[t]-v;
    if(t==255) part[blockIdx.x] = sh[255];
}

__global__ __launch_bounds__(256) void k_scan2(int* __restrict__ part){
    __shared__ int sh[256];
    int t=threadIdx.x;
    int v = (t<SCAN_NB)? part[t] : 0;
    sh[t]=v; __syncthreads();
    for(int off=1; off<256; off<<=1){
        int y=(t>=off)? sh[t-off]:0;
        __syncthreads();
        sh[t]+=y;
        __syncthreads();
    }
    if(t<SCAN_NB) part[t] = sh[t]-v;
}

__global__ __launch_bounds__(256) void k_scan3(int* __restrict__ rowptr, const int* __restrict__ part){
    int t=threadIdx.x; int i=blockIdx.x*256+t;
    if(i<N_NODES) rowptr[i] += part[blockIdx.x];
    if(i==0) rowptr[N_NODES]=N_EDGES;
}

__global__ __launch_bounds__(256) void k_fill(const int* __restrict__ src, const int* __restrict__ dst,
                                              const int* __restrict__ rowptr, const int* __restrict__ rank,
                                              int* __restrict__ col){
    int b = blockIdx.x*1024 + threadIdx.x;
    #pragma unroll
    for(int i=0;i<4;i++){
        int e = b + i*256;
        if(e < N_EDGES) col[rowptr[dst[e]] + rank[e]] = src[e];
    }
}

// Pre-split all 7 weight matrices into transposed hi/lo bf16 [n][k].
// WT offsets (shorts): m0@0(K32) m1@8192(K32) m2@16384 m3@49152 m4@81920 m5@114688 m6@147456
__global__ __launch_bounds__(256) void k_splitW(const float* __restrict__ W0, const float* __restrict__ W1,
                                                const float* __restrict__ W2, const float* __restrict__ W3,
                                                const float* __restrict__ W4, const float* __restrict__ W5,
                                                const float* __restrict__ W6, short* __restrict__ WT){
    int bx = blockIdx.x;
    int m, kc;
    if(bx < 2){ m = bx; kc = 0; }
    else { m = 2 + (bx-2)/4; kc = (bx-2)&3; }
    const float* src; int K; size_t off;
    switch(m){
        case 0: src=W0; K=32;  off=0;      break;
        case 1: src=W1; K=32;  off=8192;   break;
        case 2: src=W2; K=128; off=16384;  break;
        case 3: src=W3; K=128; off=49152;  break;
        case 4: src=W4; K=128; off=81920;  break;
        case 5: src=W5; K=128; off=114688; break;
        default:src=W6; K=128; off=147456; break;
    }
    short* hi = WT + off;
    short* lo = hi + (size_t)K*HC_DIM;
    #pragma unroll
    for(int i=0;i<16;i++){
        int idx = threadIdx.x + i*256;
        int k = kc*32 + (idx>>7);
        int n = idx & 127;
        float f = src[(size_t)k*HC_DIM + n];
        short h,l; split2(f,h,l);
        hi[(size_t)n*K + k] = h;
        lo[(size_t)n*K + k] = l;
    }
}

// h[N,32] = gelu(x[N,128] @ Win[128,32] + bin); also emits bf16 hi/lo copies.
__global__ __launch_bounds__(256) void k_gemm_in(const float* __restrict__ x, const float* __restrict__ W,
                                                 const float* __restrict__ b, float* __restrict__ h,
                                                 short* __restrict__ hhi, short* __restrict__ hlo){
    int id = blockIdx.x*256+threadIdx.x;
    int r = id>>5, c = id&31;
    const float4* x4 = (const float4*)(x + (size_t)r*IN_DIM);
    float acc=0.f;
    #pragma unroll 8
    for(int k=0;k<IN_DIM/4;k++){
        float4 xv = x4[k];
        acc = fmaf(xv.x, W[(4*k  )*HID_C+c], acc);
        acc = fmaf(xv.y, W[(4*k+1)*HID_C+c], acc);
        acc = fmaf(xv.z, W[(4*k+2)*HID_C+c], acc);
        acc = fmaf(xv.w, W[(4*k+3)*HID_C+c], acc);
    }
    float v = gelu_f(acc + b[c]);
    h[(size_t)r*HID_C+c] = v;
    short hh,ll; split2(v,hh,ll);
    hhi[(size_t)r*HID_C+c] = hh;
    hlo[(size_t)r*HID_C+c] = ll;
}

// ---------------- full-width MFMA GEMM (bf16x3, ~fp32) ----------------
// C[64 rows x 128 cols] = A@W (+pair). Details verified r6-r9.
// NORM fuses bias + row-L2-normalize -> final out. PAIR writes XR in bf16.
template<int K, bool PAIR, bool NORM>
__global__ __launch_bounds__(256) void k_mfma(const short* __restrict__ Ahi, const short* __restrict__ Alo,
                                              const short* __restrict__ WTl, const float* __restrict__ bl,
                                              const short* __restrict__ WTr, const float* __restrict__ br,
                                              float* __restrict__ XL, unsigned short* __restrict__ XR16){
    constexpr int LDS_K = 40;          // 32 + 8 pad shorts (80B rows)
    constexpr int NCH = K / 32;
    __shared__ short As_hi[64*LDS_K], As_lo[64*LDS_K];
    __shared__ short Bh0[128*LDS_K], Bl0[128*LDS_K];
    __shared__ short Bh1[PAIR?128*LDS_K:1], Bl1[PAIR?128*LDS_K:1];
    __shared__ float ssq[NORM?256:1];

    int t = threadIdx.x;
    int lane = t & 63, wave = t >> 6;
    int quad = lane >> 4, ml = lane & 15;
    int rbase = blockIdx.x * 64;

    const short* WTl_lo = WTl + (size_t)K*HC_DIM;
    const short* WTr_lo = PAIR ? (WTr + (size_t)K*HC_DIM) : nullptr;

    f32x4 accL[4][2], accR[4][2];
    #pragma unroll
    for(int i=0;i<4;i++)
        #pragma unroll
        for(int j=0;j<2;j++){ accL[i][j]=(f32x4){0,0,0,0}; accR[i][j]=(f32x4){0,0,0,0}; }

    int r = t >> 2, seg = t & 3;
    int gr = rbase + r; if(gr >= N_NODES) gr = N_NODES-1;

    for(int c=0; c<NCH; c++){
        if(c) __syncthreads();
        size_t ka = (size_t)gr*K + c*32 + seg*8;
        *(short8*)(As_hi + r*LDS_K + seg*8) = *(const short8*)(Ahi + ka);
        *(short8*)(As_lo + r*LDS_K + seg*8) = *(const short8*)(Alo + ka);
        #pragma unroll
        for(int u=0; u<2; u++){
            int uu = t + u*256;
            int n = uu >> 2, sg = uu & 3;
            size_t kw = (size_t)n*K + c*32 + sg*8;
            *(short8*)(Bh0 + n*LDS_K + sg*8) = *(const short8*)(WTl + kw);
            *(short8*)(Bl0 + n*LDS_K + sg*8) = *(const short8*)(WTl_lo + kw);
            if(PAIR){
                *(short8*)(Bh1 + n*LDS_K + sg*8) = *(const short8*)(WTr + kw);
                *(short8*)(Bl1 + n*LDS_K + sg*8) = *(const short8*)(WTr_lo + kw);
            }
        }
        __syncthreads();

        int k0 = quad*8;
        short8 ah[4], al[4];
        #pragma unroll
        for(int i=0;i<4;i++){
            ah[i] = *(const short8*)(As_hi + (16*i + ml)*LDS_K + k0);
            al[i] = *(const short8*)(As_lo + (16*i + ml)*LDS_K + k0);
        }
        #pragma unroll
        for(int j=0;j<2;j++){
            int nrow = j*64 + wave*16 + ml;
            short8 bh = *(const short8*)(Bh0 + nrow*LDS_K + k0);
            short8 blo = *(const short8*)(Bl0 + nrow*LDS_K + k0);
            #pragma unroll
            for(int i=0;i<4;i++){
                accL[i][j] = __builtin_amdgcn_mfma_f32_16x16x32_bf16(ah[i], bh,  accL[i][j], 0,0,0);
                accL[i][j] = __builtin_amdgcn_mfma_f32_16x16x32_bf16(ah[i], blo, accL[i][j], 0,0,0);
                accL[i][j] = __builtin_amdgcn_mfma_f32_16x16x32_bf16(al[i], bh,  accL[i][j], 0,0,0);
            }
            if(PAIR){
                short8 ch = *(const short8*)(Bh1 + nrow*LDS_K + k0);
                short8 cl = *(const short8*)(Bl1 + nrow*LDS_K + k0);
                #pragma unroll
                for(int i=0;i<4;i++){
                    accR[i][j] = __builtin_amdgcn_mfma_f32_16x16x32_bf16(ah[i], ch, accR[i][j], 0,0,0);
                    accR[i][j] = __builtin_amdgcn_mfma_f32_16x16x32_bf16(ah[i], cl, accR[i][j], 0,0,0);
                    accR[i][j] = __builtin_amdgcn_mfma_f32_16x16x32_bf16(al[i], ch, accR[i][j], 0,0,0);
                }
            }
        }
    }

    int col0 = wave*16 + ml, col1 = 64 + wave*16 + ml;
    float bL0 = bl[col0], bL1 = bl[col1];

    if(NORM){
        #pragma unroll
        for(int i=0;i<4;i++){
            #pragma unroll
            for(int rr=0;rr<4;rr++){
                float v0 = accL[i][0][rr] + bL0;
                float v1 = accL[i][1][rr] + bL1;
                float p = v0*v0 + v1*v1;
                p += __shfl_xor(p,1); p += __shfl_xor(p,2);
                p += __shfl_xor(p,4); p += __shfl_xor(p,8);
                if(ml==0) ssq[wave*64 + 16*i + quad*4 + rr] = p;
            }
        }
        __syncthreads();
        #pragma unroll
        for(int i=0;i<4;i++){
            #pragma unroll
            for(int rr=0;rr<4;rr++){
                int row = 16*i + quad*4 + rr;
                int grr = rbase + row;
                if(grr < N_NODES){
                    float tot = ssq[row] + ssq[64+row] + ssq[128+row] + ssq[192+row];
                    float inv = 1.0f / fmaxf(sqrtf(tot), 1e-12f);
                    XL[(size_t)grr*HC_DIM + col0] = (accL[i][0][rr] + bL0) * inv;
                    XL[(size_t)grr*HC_DIM + col1] = (accL[i][1][rr] + bL1) * inv;
                }
            }
        }
    } else {
        float bR0 = PAIR ? br[col0] : 0.f, bR1 = PAIR ? br[col1] : 0.f;
        #pragma unroll
        for(int i=0;i<4;i++){
            #pragma unroll
            for(int rr=0;rr<4;rr++){
                int grr = rbase + 16*i + quad*4 + rr;
                if(grr < N_NODES){
                    XL[(size_t)grr*HC_DIM + col0] = accL[i][0][rr] + bL0;
                    XL[(size_t)grr*HC_DIM + col1] = accL[i][1][rr] + bL1;
                    if(PAIR){
                        XR16[(size_t)grr*HC_DIM + col0] = f2bf(accR[i][0][rr] + bR0);
                        XR16[(size_t)grr*HC_DIM + col1] = f2bf(accR[i][1][rr] + bR1);
                    }
                }
            }
        }
    }
}

// ---------------- fused per-node GATv2 (XR bf16, VALU-lean) ----------------
// r9: VALUBusy 96% -> instruction diet: leaky as fmaxf(x,0.2x) (2 inst),
// att pre-scaled by log2e + exp2f (kills hidden mul per exp), masked-batch tail
// (1 batched update instead of up-to-7 sequential ones).
__global__ __launch_bounds__(256) void k_node(const float* __restrict__ XL, const unsigned short* __restrict__ XR,
    const int* __restrict__ rowptr, const int* __restrict__ colidx,
    const float* __restrict__ att, const float* __restrict__ bo,
    const float* __restrict__ gg, const float* __restrict__ be,
    const float* __restrict__ hold, float* __restrict__ hout,
    short* __restrict__ hi_out, short* __restrict__ lo_out)
{
    int wave=threadIdx.x>>6, lane=threadIdx.x&63;
    int node = blockIdx.x*4+wave;
    int cg = lane & 31, half = lane >> 5;
    int c4 = cg << 2;

    float4 xl = *(const float4*)(XL + (size_t)node*HC_DIM + c4);
    float4 av = *(const float4*)(att + c4);
    av.x *= LOG2E; av.y *= LOG2E; av.z *= LOG2E; av.w *= LOG2E;   // logits in log2 domain
    int beg = rowptr[node], end = rowptr[node+1];

    #define LOADX(j, xx) { ushort4 u_ = *(const ushort4*)(XR + (size_t)(j)*HC_DIM + c4); \
        xx = make_float4(bf2f(u_.x), bf2f(u_.y), bf2f(u_.z), bf2f(u_.w)); }
    #define EDGE_LOGIT(xj, q) { \
        float u0 = xl.x + xj.x; u0 = fmaxf(u0, 0.2f*u0); \
        float u1 = xl.y + xj.y; u1 = fmaxf(u1, 0.2f*u1); \
        float u2 = xl.z + xj.z; u2 = fmaxf(u2, 0.2f*u2); \
        float u3 = xl.w + xj.w; u3 = fmaxf(u3, 0.2f*u3); \
        q = fmaf(u0,av.x, fmaf(u1,av.y, fmaf(u2,av.z, u3*av.w))); \
        q += __shfl_xor(q,1); q += __shfl_xor(q,2); q += __shfl_xor(q,4); }

    float4 xs; LOADX(node, xs)
    float qs; EDGE_LOGIT(xs, qs)
    float m, ls; float4 acc;
    if(half==0){ m = qs; ls = 1.f; acc = xs; }
    else       { m = -INFINITY; ls = 0.f; acc = make_float4(0.f,0.f,0.f,0.f); }

    int P = end - beg;
    int nb = P >> 3;
    int base = beg;
    for(int b=0; b<nb; b++, base += 8){
        int j0 = colidx[base     + half];
        int j1 = colidx[base + 2 + half];
        int j2 = colidx[base + 4 + half];
        int j3 = colidx[base + 6 + half];
        float4 x0, x1, x2, x3;
        LOADX(j0, x0) LOADX(j1, x1) LOADX(j2, x2) LOADX(j3, x3)
        float q0,q1,q2,q3;
        EDGE_LOGIT(x0,q0) EDGE_LOGIT(x1,q1) EDGE_LOGIT(x2,q2) EDGE_LOGIT(x3,q3)
        float nm = fmaxf(m, fmaxf(fmaxf(q0,q1),fmaxf(q2,q3)));
        float sc = exp2f(m-nm);
        float e0 = exp2f(q0-nm), e1 = exp2f(q1-nm);
        float e2 = exp2f(q2-nm), e3 = exp2f(q3-nm);
        ls = fmaf(ls, sc, (e0+e1)+(e2+e3));
        acc.x = fmaf(acc.x, sc, fmaf(e0,x0.x, fmaf(e1,x1.x, fmaf(e2,x2.x, e3*x3.x))));
        acc.y = fmaf(acc.y, sc, fmaf(e0,x0.y, fmaf(e1,x1.y, fmaf(e2,x2.y, e3*x3.y))));
        acc.z = fmaf(acc.z, sc, fmaf(e0,x0.z, fmaf(e1,x1.z, fmaf(e2,x2.z, e3*x3.z))));
        acc.w = fmaf(acc.w, sc, fmaf(e0,x0.w, fmaf(e1,x1.w, fmaf(e2,x2.w, e3*x3.w))));
        m = nm;
    }
    // masked tail batch: up to 7 remaining edges in ONE batched update.
    // inactive slots get q=-inf -> e=0 -> no contribution (loads clamped to node row).
    if(base < end){
        int i0 = base + half, i1 = base + 2 + half, i2 = base + 4 + half, i3 = base + 6 + half;
        int j0 = (i0<end)? colidx[i0] : node;
        int j1 = (i1<end)? colidx[i1] : node;
        int j2 = (i2<end)? colidx[i2] : node;
        int j3 = (i3<end)? colidx[i3] : node;
        float4 x0, x1, x2, x3;
        LOADX(j0, x0) LOADX(j1, x1) LOADX(j2, x2) LOADX(j3, x3)
        float q0,q1,q2,q3;
        EDGE_LOGIT(x0,q0) EDGE_LOGIT(x1,q1) EDGE_LOGIT(x2,q2) EDGE_LOGIT(x3,q3)
        if(i1>=end) q1 = -INFINITY;
        if(i2>=end) q2 = -INFINITY;
        if(i3>=end) q3 = -INFINITY;
        if(i0 < end){   // this half has >=1 active slot (q0 finite -> nm finite)
            float nm = fmaxf(m, fmaxf(fmaxf(q0,q1),fmaxf(q2,q3)));
            float sc = exp2f(m-nm);
            float e0 = exp2f(q0-nm), e1 = exp2f(q1-nm);
            float e2 = exp2f(q2-nm), e3 = exp2f(q3-nm);
            ls = fmaf(ls, sc, (e0+e1)+(e2+e3));
            acc.x = fmaf(acc.x, sc, fmaf(e0,x0.x, fmaf(e1,x1.x, fmaf(e2,x2.x, e3*x3.x))));
            acc.y = fmaf(acc.y, sc, fmaf(e0,x0.y, fmaf(e1,x1.y, fmaf(e2,x2.y, e3*x3.y))));
            acc.z = fmaf(acc.z, sc, fmaf(e0,x0.z, fmaf(e1,x1.z, fmaf(e2,x2.z, e3*x3.z))));
            acc.w = fmaf(acc.w, sc, fmaf(e0,x0.w, fmaf(e1,x1.w, fmaf(e2,x2.w, e3*x3.w))));
            m = nm;
        }
    }
    #undef EDGE_LOGIT
    #undef LOADX

    {   // merge the two half-wave softmax states
        float mo  = __shfl_xor(m, 32);
        float lso = __shfl_xor(ls, 32);
        float4 ao;
        ao.x = __shfl_xor(acc.x,32); ao.y = __shfl_xor(acc.y,32);
        ao.z = __shfl_xor(acc.z,32); ao.w = __shfl_xor(acc.w,32);
        float nm = fmaxf(m, mo);
        float s0 = exp2f(m-nm), s1 = exp2f(mo-nm);
        ls = ls*s0 + lso*s1;
        acc.x = acc.x*s0 + ao.x*s1;
        acc.y = acc.y*s0 + ao.y*s1;
        acc.z = acc.z*s0 + ao.z*s1;
        acc.w = acc.w*s0 + ao.w*s1;
    }

    float inv = 1.0f/ls;
    float4 bo4 = *(const float4*)(bo + c4);
    float o0 = fmaf(acc.x,inv,bo4.x), o1 = fmaf(acc.y,inv,bo4.y);
    float o2 = fmaf(acc.z,inv,bo4.z), o3 = fmaf(acc.w,inv,bo4.w);
    float s1v = (o0+o1)+(o2+o3);
    float s2v = fmaf(o0,o0, fmaf(o1,o1, fmaf(o2,o2, o3*o3)));
    #pragma unroll
    for(int msk=1;msk<32;msk<<=1){ s1v += __shfl_xor(s1v,msk); s2v += __shfl_xor(s2v,msk); }
    float mean = s1v*(1.f/128.f);
    float var  = s2v*(1.f/128.f) - mean*mean;
    float rstd = rsqrtf(var + 1e-5f);
    float4 g4  = *(const float4*)(gg + c4);
    float4 be4 = *(const float4*)(be + c4);
    float r0 = gelu_f(fmaf(g4.x*(o0-mean), rstd, be4.x));
    float r1 = gelu_f(fmaf(g4.y*(o1-mean), rstd, be4.y));
    float r2 = gelu_f(fmaf(g4.z*(o2-mean), rstd, be4.z));
    float r3 = gelu_f(fmaf(g4.w*(o3-mean), rstd, be4.w));
    if(hold){
        float4 hv = *(const float4*)(hold + (size_t)node*HC_DIM + c4);
        r0 += hv.x; r1 += hv.y; r2 += hv.z; r3 += hv.w;
    }
    if(half==0){
        *(float4*)(hout + (size_t)node*HC_DIM + c4) = make_float4(r0,r1,r2,r3);
        short4v vh, vl; short hh, ll;
        split2(r0,hh,ll); vh[0]=hh; vl[0]=ll;
        split2(r1,hh,ll); vh[1]=hh; vl[1]=ll;
        split2(r2,hh,ll); vh[2]=hh; vl[2]=ll;
        split2(r3,hh,ll); vh[3]=hh; vl[3]=ll;
        *(short4v*)(hi_out + (size_t)node*HC_DIM + c4) = vh;
        *(short4v*)(lo_out + (size_t)node*HC_DIM + c4) = vl;
    }
}

extern "C" void kernel_launch(void* const* d_in, const int* in_sizes, int n_in,
                              void* d_out, int out_size, void* d_ws, size_t ws_size,
                              hipStream_t stream)
{
    const float* x   = (const float*)d_in[0];
    const int*   ei  = (const int*)  d_in[1];
    const float* Win = (const float*)d_in[2];
    const float* bin = (const float*)d_in[3];
    const float *Wl[3], *bl[3], *Wr[3], *br[3], *att[3], *bo[3], *gg[3], *be[3];
    for(int i=0;i<3;i++){
        const int base = 4 + 8*i;
        Wl[i]=(const float*)d_in[base+0]; bl[i]=(const float*)d_in[base+1];
        Wr[i]=(const float*)d_in[base+2]; br[i]=(const float*)d_in[base+3];
        att[i]=(const float*)d_in[base+4]; bo[i]=(const float*)d_in[base+5];
        gg[i]=(const float*)d_in[base+6]; be[i]=(const float*)d_in[base+7];
    }
    const float* Wout=(const float*)d_in[28];
    const float* bout=(const float*)d_in[29];
    float* out = (float*)d_out;

    char* w = (char*)d_ws;
    float* hA = (float*)w;  w += (size_t)N_NODES*HC_DIM*4;
    float* hB = (float*)w;  w += (size_t)N_NODES*HC_DIM*4;
    float* XL = (float*)w;  w += (size_t)N_NODES*HC_DIM*4;
    unsigned short* XR16 = (unsigned short*)w; w += (size_t)N_NODES*HC_DIM*2;
    short* hAhi = (short*)w; w += (size_t)N_NODES*HC_DIM*2;
    short* hAlo = (short*)w; w += (size_t)N_NODES*HC_DIM*2;
    short* hBhi = (short*)w; w += (size_t)N_NODES*HC_DIM*2;
    short* hBlo = (short*)w; w += (size_t)N_NODES*HC_DIM*2;
    short* WT   = (short*)w; w += (size_t)180224*2;
    int* rowptr = (int*)w;  w += (size_t)(N_NODES+2)*4;
    int* cursor = (int*)w;  w += (size_t)N_NODES*4;
    int* colidx = (int*)w;  w += (size_t)N_EDGES*4;
    int* rank   = (int*)w;  w += (size_t)N_EDGES*4;
    int* part   = (int*)w;  w += 256*4;

    const int* srcp = ei;
    const int* dstp = ei + N_EDGES;

    const short* WTl0 = WT + 0;      const short* WTr0 = WT + 8192;
    const short* WTl1 = WT + 16384;  const short* WTr1 = WT + 49152;
    const short* WTl2 = WT + 81920;  const short* WTr2 = WT + 114688;
    const short* WTo  = WT + 147456;

    // ---- weight split + CSR build + input projection (stream-ordered small dispatches) ----
    k_splitW<<<22,256,0,stream>>>(Wl[0],Wr[0],Wl[1],Wr[1],Wl[2],Wr[2],Wout, WT);
    hipMemsetAsync(cursor, 0, (size_t)N_NODES*4, stream);
    k_count <<<782,256, 0, stream>>>(dstp, cursor, rank);
    k_scan1 <<<SCAN_NB,256,0,stream>>>(cursor, rowptr, part);
    k_scan2 <<<1,   256, 0, stream>>>(part);
    k_scan3 <<<SCAN_NB,256,0,stream>>>(rowptr, part);
    k_fill  <<<782,256, 0, stream>>>(srcp, dstp, rowptr, rank, colidx);
    k_gemm_in<<<6250,256,0,stream>>>(x, Win, bin, hA, hAhi, hAlo);

    // ---- layer 0: hA[N,32] -> hB[N,128] (no residual) ----
    k_mfma<32,true,false><<<782,256,0,stream>>>(hAhi, hAlo, WTl0, bl[0], WTr0, br[0], XL, XR16);
    k_node<<<12500,256,0,stream>>>(XL,XR16,rowptr,colidx,att[0],bo[0],gg[0],be[0],
                                   (const float*)nullptr, hB, hBhi, hBlo);

    // ---- layer 1: hB -> hA (residual hB) ----
    k_mfma<128,true,false><<<782,256,0,stream>>>(hBhi, hBlo, WTl1, bl[1], WTr1, br[1], XL, XR16);
    k_node<<<12500,256,0,stream>>>(XL,XR16,rowptr,colidx,att[1],bo[1],gg[1],be[1], hB, hA, hAhi, hAlo);

    // ---- layer 2: hA -> hB (residual hA) ----
    k_mfma<128,true,false><<<782,256,0,stream>>>(hAhi, hAlo, WTl2, bl[2], WTr2, br[2], XL, XR16);
    k_node<<<12500,256,0,stream>>>(XL,XR16,rowptr,colidx,att[2],bo[2],gg[2],be[2], hA, hB, hBhi, hBlo);

    // ---- output projection + fused row L2-normalize -> out ----
    k_mfma<128,false,true><<<782,256,0,stream>>>(hBhi, hBlo, WTo, bout, nullptr, nullptr, out, nullptr);
}